// Round 5
// baseline (227.383 us; speedup 1.0000x reference)
//
#include <hip/hip_runtime.h>

// interactionModule: LJ force message passing on a random graph.
//   dr = x[dst]-x[src]; r=|dr|; rc=max(r,0.1)
//   f = 4*(1/rc)^6*(12*(1/rc)^6-6)/rc ; msg = f*dr/max(r,1e-12)
//   out[dst] += msg (segment sum);  out -= 0.1*v
//
// R1: 12.8M global f32 atomics -> 641us (32B txn each, memory-side).
// R2: scattered 4B record writes -> 155us bin (same txn wall, write side).
// R3/R4: dst-bucket counting sort + LDS agg: 219 -> 205us. R4 falsified the
//   occupancy theory: agg flat at 91us from 23%->64% occupancy => per-CU
//   L2-txn throughput (~4cyc/lane for divergent ops) + LDS bank conflicts
//   (interleaved acc -> even-bank 4-way) are the walls.
// R5: 2D tiles (src-range 4096 x dst-range 2048, 25x49=1225 tiles). Sort by
//   tile key once; tile kernel stages BOTH x-slices + acc in LDS (SoA,
//   conflict-free) => ZERO divergent vector-memory in the whole pipeline.
//   Tile partials alias the tile's own (consumed) records segment.

constexpr float GAMMA = 0.1f;
constexpr float MIN_R = 0.1f;
constexpr float EPSN  = 1e-12f;

constexpr int SS   = 12;              // src-range shift (4096 nodes)
constexpr int DS   = 11;              // dst-range shift (2048 nodes)
constexpr int SRCR = 1 << SS;         // 4096
constexpr int DSTR = 1 << DS;         // 2048
constexpr int NS   = 25;              // ceil(100000/4096)
constexpr int ND   = 49;              // ceil(100000/2048)
constexpr int NT   = NS * ND;         // 1225 tiles
constexpr int NTA  = 1232;            // padded array length
constexpr int CHUNK    = 16384;       // edges per sort block
constexpr int STHREADS = 1024;
constexpr int CAP_T    = 6400;        // records cap per tile
                                      // lambda 5956 incl pad, 6-sigma margin
constexpr unsigned SENT = 0xFFFFFFFFu;

__device__ __forceinline__ float2 lj_msg(float xsx, float xsy, float xdx, float xdy) {
    float dx = xdx - xsx;
    float dy = xdy - xsy;
    float ab = sqrtf(dx * dx + dy * dy);      // |dr| unclamped
    float r  = ab > MIN_R ? ab : MIN_R;       // clamp for force only
    float inv = 1.0f / r;
    float s2 = inv * inv;
    float s6 = s2 * s2 * s2;                  // (1/r)^6
    float f  = 4.0f * s6 * (12.0f * s6 - 6.0f) * inv;
    float c  = f / fmaxf(ab, EPSN);           // F.normalize eps
    return make_float2(c * dx, c * dy);
}

__global__ __launch_bounds__(256) void zero_kernel(unsigned* __restrict__ p, int n) {
    int i = blockIdx.x * blockDim.x + threadIdx.x;
    if (i < n) p[i] = 0u;
}

// ---- Pass 1: block-local counting sort by 2D tile key ---------------------
__global__ __launch_bounds__(STHREADS) void sort_kernel(
    const int4* __restrict__ src4, const int4* __restrict__ dst4,
    unsigned* __restrict__ records, unsigned* __restrict__ gcur, int nE)
{
    __shared__ unsigned sorted[CHUNK];    // 64 KB
    __shared__ unsigned cnt[NTA];         // ~4.9 KB each
    __shared__ unsigned curs[NTA];
    __shared__ unsigned gbase[NTA];

    const int t = threadIdx.x;
    const int base4 = blockIdx.x * (CHUNK / 4);

    for (int i = t; i < NTA; i += STHREADS) cnt[i] = 0u;
    __syncthreads();

    // Phase A: count tile keys (indices stay L2-hot for the re-read).
#pragma unroll
    for (int i = 0; i < CHUNK / (4 * STHREADS); ++i) {
        int idx4 = base4 + i * STHREADS + t;
        if (idx4 * 4 < nE) {
            int4 s4 = src4[idx4];
            int4 d4 = dst4[idx4];
            atomicAdd(&cnt[(s4.x >> SS) * ND + (d4.x >> DS)], 1u);
            atomicAdd(&cnt[(s4.y >> SS) * ND + (d4.y >> DS)], 1u);
            atomicAdd(&cnt[(s4.z >> SS) * ND + (d4.z >> DS)], 1u);
            atomicAdd(&cnt[(s4.w >> SS) * ND + (d4.w >> DS)], 1u);
        }
    }
    __syncthreads();

    // Phase B: Hillis-Steele inclusive scan over NT (2 elems/thread).
    {
        int i0 = t, i1 = t + STHREADS;
        if (i0 < NT) curs[i0] = cnt[i0];
        if (i1 < NT) curs[i1] = cnt[i1];
    }
    __syncthreads();
    for (int off = 1; off < NT; off <<= 1) {
        unsigned a0 = 0, a1 = 0;
        int i0 = t, i1 = t + STHREADS;
        if (i0 < NT) a0 = curs[i0] + ((i0 >= off) ? curs[i0 - off] : 0u);
        if (i1 < NT) a1 = curs[i1] + ((i1 >= off) ? curs[i1 - off] : 0u);
        __syncthreads();
        if (i0 < NT) curs[i0] = a0;
        if (i1 < NT) curs[i1] = a1;
        __syncthreads();
    }

    // Phase C: exclusive cursor + reserve 16B-aligned global ranges.
    for (int b = t; b < NT; b += STHREADS) {
        unsigned c = cnt[b];
        curs[b] -= c;                              // inclusive -> exclusive
        unsigned pc = (c + 3u) & ~3u;              // pad to 4 u32 = 16 B
        gbase[b] = pc ? atomicAdd(&gcur[b], pc) : 0u;
    }
    __syncthreads();

    // Phase D: re-read edges (L2-hot), place tile-sorted into LDS.
#pragma unroll
    for (int i = 0; i < CHUNK / (4 * STHREADS); ++i) {
        int idx4 = base4 + i * STHREADS + t;
        if (idx4 * 4 < nE) {
            int4 s4 = src4[idx4];
            int4 d4 = dst4[idx4];
            int ss_[4] = {s4.x, s4.y, s4.z, s4.w};
            int dd_[4] = {d4.x, d4.y, d4.z, d4.w};
#pragma unroll
            for (int k = 0; k < 4; ++k) {
                int b = (ss_[k] >> SS) * ND + (dd_[k] >> DS);
                unsigned rec = ((unsigned)(ss_[k] & (SRCR - 1)) << DS)
                             | (unsigned)(dd_[k] & (DSTR - 1));
                unsigned slot = atomicAdd(&curs[b], 1u);   // ds_add_rtn_u32
                sorted[slot] = rec;
            }
        }
    }
    __syncthreads();
    // curs[b] is inclusive again; LDS segment start = curs[b] - cnt[b].

    // Phase E: flush, one wave per tile; sentinel-pad to 16B multiple.
    const int wave = t >> 6, lane = t & 63;
    for (int b = wave; b < NT; b += STHREADS / 64) {
        unsigned c = cnt[b];
        if (!c) continue;
        unsigned pc = (c + 3u) & ~3u;
        unsigned p = curs[b] - c;
        unsigned g = gbase[b];
        unsigned* rb = records + (size_t)b * CAP_T;
        for (unsigned i = lane; i < pc; i += 64) {
            unsigned go = g + i;
            if (go < (unsigned)CAP_T) rb[go] = (i < c) ? sorted[p + i] : SENT;
        }
    }
}

// ---- Pass 2: one block per tile; both x-slices + acc in LDS (SoA) ---------
__global__ __launch_bounds__(512) void tile_kernel(
    const float2* __restrict__ x, unsigned* __restrict__ records,
    const unsigned* __restrict__ gcur, int N)
{
    __shared__ float xs_x[SRCR], xs_y[SRCR];    // 32 KB src slice
    __shared__ float xd_x[DSTR], xd_y[DSTR];    // 16 KB dst slice
    __shared__ float acc_x[DSTR], acc_y[DSTR];  // 16 KB accumulator

    const int tile = blockIdx.x;
    const int sr = tile / ND, dr = tile % ND;
    const int s0 = sr << SS, d0 = dr << DS;

    for (int i = threadIdx.x; i < SRCR; i += 512) {
        int n = s0 + i;
        float2 p = (n < N) ? x[n] : make_float2(0.f, 0.f);
        xs_x[i] = p.x; xs_y[i] = p.y;
    }
    for (int i = threadIdx.x; i < DSTR; i += 512) {
        int n = d0 + i;
        float2 p = (n < N) ? x[n] : make_float2(0.f, 0.f);
        xd_x[i] = p.x; xd_y[i] = p.y;
        acc_x[i] = 0.f; acc_y[i] = 0.f;
    }
    __syncthreads();

    const unsigned total = min(gcur[tile], (unsigned)CAP_T) & ~3u;
    const uint4* r4 = (const uint4*)(records + (size_t)tile * CAP_T);
    for (unsigned j = threadIdx.x; j < (total >> 2); j += 512) {
        uint4 rr = r4[j];
        unsigned rs[4] = {rr.x, rr.y, rr.z, rr.w};
#pragma unroll
        for (int k = 0; k < 4; ++k) {
            unsigned rec = rs[k];
            if (rec != SENT) {
                int sl = (int)(rec >> DS);
                int dl = (int)(rec & (DSTR - 1));
                float2 m = lj_msg(xs_x[sl], xs_y[sl], xd_x[dl], xd_y[dl]);
                atomicAdd(&acc_x[dl], m.x);     // ds_add_f32, banks spread
                atomicAdd(&acc_y[dl], m.y);
            }
        }
    }
    __syncthreads();

    // Flush partials into our OWN (fully consumed) records segment:
    // 2*DSTR floats = 16 KB <= CAP_T*4 = 25.6 KB. No cross-block hazard.
    float* pt = (float*)(records + (size_t)tile * CAP_T);
    for (int i = threadIdx.x; i < DSTR; i += 512) {
        pt[i]        = acc_x[i];
        pt[DSTR + i] = acc_y[i];
    }
}

// ---- Pass 3: fold NS partials per node + fuse -gamma*v --------------------
__global__ __launch_bounds__(256) void reduce_kernel(
    const float* __restrict__ partials, const float2* __restrict__ v,
    float2* __restrict__ out, int N)
{
    int n = blockIdx.x * 256 + threadIdx.x;
    if (n >= N) return;
    int dr = n >> DS, dl = n & (DSTR - 1);
    float sx = 0.f, sy = 0.f;
#pragma unroll
    for (int sr = 0; sr < NS; ++sr) {
        const float* pt = partials + (size_t)(sr * ND + dr) * CAP_T;
        sx += pt[dl];
        sy += pt[DSTR + dl];
    }
    float2 vv = v[n];
    out[n] = make_float2(sx - GAMMA * vv.x, sy - GAMMA * vv.y);
}

// ---- Fallback (round-1 path) ----------------------------------------------
__global__ __launch_bounds__(256) void init_kernel(const float4* __restrict__ v,
                                                   float4* __restrict__ out,
                                                   int n4) {
    int i = blockIdx.x * blockDim.x + threadIdx.x;
    if (i < n4) {
        float4 t = v[i];
        out[i] = make_float4(-GAMMA * t.x, -GAMMA * t.y, -GAMMA * t.z, -GAMMA * t.w);
    }
}

__global__ __launch_bounds__(256) void edge_atomic_kernel(
    const float2* __restrict__ x, const int* __restrict__ src,
    const int* __restrict__ dst, float* __restrict__ out, int nE)
{
    int e = blockIdx.x * blockDim.x + threadIdx.x;
    if (e >= nE) return;
    int s = src[e], d = dst[e];
    float2 m = lj_msg(x[s].x, x[s].y, x[d].x, x[d].y);
    unsafeAtomicAdd(&out[2 * d],     m.x);
    unsafeAtomicAdd(&out[2 * d + 1], m.y);
}

extern "C" void kernel_launch(void* const* d_in, const int* in_sizes, int n_in,
                              void* d_out, int out_size, void* d_ws, size_t ws_size,
                              hipStream_t stream) {
    const float* x   = (const float*)d_in[0];
    const float* v   = (const float*)d_in[1];
    const int*   src = (const int*)d_in[2];
    const int*   dst = (const int*)d_in[3];
    float* out = (float*)d_out;

    const int nE = in_sizes[2];                 // 6,400,000
    const int N  = in_sizes[0] / 2;             // 100,000

    const size_t gcur_bytes    = 8192;          // NTA u32, 16B-aligned pad
    const size_t records_bytes = (size_t)NT * CAP_T * sizeof(unsigned); // 31.4MB
    const size_t needed = gcur_bytes + records_bytes;

    const bool shapes_ok = (N <= NS * SRCR) && (N <= ND * DSTR) && (nE % 4) == 0;

    if (shapes_ok && ws_size >= needed) {
        unsigned* gcur    = (unsigned*)d_ws;
        unsigned* records = (unsigned*)((char*)d_ws + gcur_bytes);
        const int nblk = (nE + CHUNK - 1) / CHUNK;   // 391

        zero_kernel<<<(NTA + 255) / 256, 256, 0, stream>>>(gcur, NTA);
        sort_kernel<<<nblk, STHREADS, 0, stream>>>(
            (const int4*)src, (const int4*)dst, records, gcur, nE);
        tile_kernel<<<NT, 512, 0, stream>>>(
            (const float2*)x, records, gcur, N);
        reduce_kernel<<<(N + 255) / 256, 256, 0, stream>>>(
            (const float*)records, (const float2*)v, (float2*)out, N);
    } else {
        int n4 = out_size / 4;
        init_kernel<<<(n4 + 255) / 256, 256, 0, stream>>>(
            (const float4*)v, (float4*)out, n4);
        edge_atomic_kernel<<<(nE + 255) / 256, 256, 0, stream>>>(
            (const float2*)x, src, dst, out, nE);
    }
}

// Round 6
// 178.738 us; speedup vs baseline: 1.2722x; 1.2722x over previous
//
#include <hip/hip_runtime.h>

// interactionModule: LJ force message passing on a random graph.
//   dr = x[dst]-x[src]; r=|dr|; rc=max(r,0.1)
//   f = 4*(1/rc)^6*(12*(1/rc)^6-6)/rc ; msg = f*dr/max(r,1e-12)
//   out[dst] += msg (segment sum);  out -= 0.1*v
//
// R1: 12.8M global f32 atomics -> 641us. R2: scattered writes -> 155us bin.
// R3-R5: agg/tile stuck at ~90us across 3 different structures; sort ~110us.
//   Unified law (R5): LDS atomic lane-ops cost ~4.3 cyc/lane/CU. Both
//   kernels sit on that wall (2 atomic lane-ops per edge each).
// R6: halve atomics per kernel:
//   sort v2: ds_add_rtn count+stash slot in regs -> placement atomic-free.
//   tile v2: dl-histogram (1 u32 atomic/edge) + scan + atomic-free placement
//            + per-thread register reduction (fp LDS atomics: 12.8M -> 0).

constexpr float GAMMA = 0.1f;
constexpr float MIN_R = 0.1f;
constexpr float EPSN  = 1e-12f;

constexpr int SS   = 12;              // src-range shift (4096 nodes)
constexpr int DSH  = 11;              // dst-range shift (2048 nodes)
constexpr int SRCR = 1 << SS;         // 4096
constexpr int DSTR = 1 << DSH;        // 2048
constexpr int NS   = 25;              // ceil(100000/4096)
constexpr int ND   = 49;              // ceil(100000/2048)
constexpr int NT   = NS * ND;         // 1225 tiles
constexpr int NTA  = 1232;            // padded
constexpr int CHUNK    = 16384;       // edges per sort block
constexpr int STHREADS = 1024;
constexpr int K        = CHUNK / STHREADS;   // 16 edges/thread
constexpr int CAP_T    = 6400;        // records cap per tile (mean ~5811 incl
                                      // 16B pad, ~7.7 sigma margin)
constexpr unsigned SENT = 0xFFFFFFFFu;

__device__ __forceinline__ float2 lj_msg(float xsx, float xsy, float xdx, float xdy) {
    float dx = xdx - xsx;
    float dy = xdy - xsy;
    float ab = sqrtf(dx * dx + dy * dy);      // |dr| unclamped
    float r  = ab > MIN_R ? ab : MIN_R;       // clamp for force only
    float inv = 1.0f / r;
    float s2 = inv * inv;
    float s6 = s2 * s2 * s2;                  // (1/r)^6
    float f  = 4.0f * s6 * (12.0f * s6 - 6.0f) * inv;
    float c  = f / fmaxf(ab, EPSN);           // F.normalize eps
    return make_float2(c * dx, c * dy);
}

__global__ __launch_bounds__(256) void zero_kernel(unsigned* __restrict__ p, int n) {
    int i = blockIdx.x * blockDim.x + threadIdx.x;
    if (i < n) p[i] = 0u;
}

// ---- Pass 1: counting sort by 2D tile key; ONE atomic per edge ------------
__global__ __launch_bounds__(STHREADS) void sort_kernel(
    const int4* __restrict__ src4, const int4* __restrict__ dst4,
    unsigned* __restrict__ records, unsigned* __restrict__ gcur, int nE)
{
    __shared__ unsigned sorted[CHUNK];    // 64 KB
    __shared__ unsigned cnt[NTA];         // 4.9 KB
    __shared__ unsigned curs[NTA];        // 4.9 KB (exclusive starts)
    __shared__ unsigned gbase[NTA];       // 4.9 KB

    const int t = threadIdx.x;
    const int base4 = blockIdx.x * (CHUNK / 4);

    for (int i = t; i < NTA; i += STHREADS) cnt[i] = 0u;
    __syncthreads();

    // Phase A: single read; count via ds_add_rtn, stash (rec, slot) in regs.
    unsigned rc[K];                       // record, SENT = invalid
    unsigned bb[K];                       // tile key
    unsigned sl[K];                       // slot within (block, tile)
#pragma unroll
    for (int i = 0; i < K / 4; ++i) {
        int idx4 = base4 + i * STHREADS + t;
        bool vld = (idx4 * 4) < nE;
        int4 s4 = vld ? src4[idx4] : make_int4(0, 0, 0, 0);
        int4 d4 = vld ? dst4[idx4] : make_int4(0, 0, 0, 0);
        int ss_[4] = {s4.x, s4.y, s4.z, s4.w};
        int dd_[4] = {d4.x, d4.y, d4.z, d4.w};
#pragma unroll
        for (int k = 0; k < 4; ++k) {
            int j = i * 4 + k;
            if (vld) {
                unsigned b = (unsigned)((ss_[k] >> SS) * ND + (dd_[k] >> DSH));
                rc[j] = ((unsigned)(ss_[k] & (SRCR - 1)) << DSH)
                      | (unsigned)(dd_[k] & (DSTR - 1));
                bb[j] = b;
                sl[j] = atomicAdd(&cnt[b], 1u);   // ds_add_rtn_u32
            } else {
                rc[j] = SENT; bb[j] = SENT;
            }
        }
    }
    __syncthreads();

    // Phase B: Hillis-Steele inclusive scan (2 elems/thread) into curs.
    {
        int i0 = t, i1 = t + STHREADS;
        if (i0 < NT) curs[i0] = cnt[i0];
        if (i1 < NT) curs[i1] = cnt[i1];
    }
    __syncthreads();
    for (int off = 1; off < NT; off <<= 1) {
        unsigned a0 = 0, a1 = 0;
        int i0 = t, i1 = t + STHREADS;
        if (i0 < NT) a0 = curs[i0] + ((i0 >= off) ? curs[i0 - off] : 0u);
        if (i1 < NT) a1 = curs[i1] + ((i1 >= off) ? curs[i1 - off] : 0u);
        __syncthreads();
        if (i0 < NT) curs[i0] = a0;
        if (i1 < NT) curs[i1] = a1;
        __syncthreads();
    }

    // Phase C: exclusive starts + reserve 16B-aligned global ranges.
    for (int b = t; b < NT; b += STHREADS) {
        unsigned c = cnt[b];
        curs[b] -= c;                              // inclusive -> exclusive
        unsigned pc = (c + 3u) & ~3u;              // pad to 4 u32 = 16 B
        gbase[b] = pc ? atomicAdd(&gcur[b], pc) : 0u;
    }
    __syncthreads();

    // Phase D: atomic-free placement (excl start + stashed slot).
#pragma unroll
    for (int j = 0; j < K; ++j)
        if (bb[j] != SENT) sorted[curs[bb[j]] + sl[j]] = rc[j];
    __syncthreads();

    // Phase E: flush, one wave per tile; sentinel-pad to 16B multiple.
    const int wave = t >> 6, lane = t & 63;
    for (int b = wave; b < NT; b += STHREADS / 64) {
        unsigned c = cnt[b];
        if (!c) continue;
        unsigned pc = (c + 3u) & ~3u;
        unsigned p = curs[b];                      // exclusive start
        unsigned g = gbase[b];
        unsigned* rb = records + (size_t)b * CAP_T;
        for (unsigned i = lane; i < pc; i += 64) {
            unsigned go = g + i;
            if (go < (unsigned)CAP_T) rb[go] = (i < c) ? sorted[p + i] : SENT;
        }
    }
}

// ---- Pass 2: per tile: dl-sort (1 atomic/edge) + register reduction -------
__global__ __launch_bounds__(512) void tile_kernel(
    const float2* __restrict__ x, unsigned* __restrict__ records,
    const unsigned* __restrict__ gcur, int N)
{
    __shared__ float    xs_x[SRCR], xs_y[SRCR];  // 32 KB src slice
    __shared__ unsigned cnt[DSTR];               // 8 KB per-dl counts
    __shared__ unsigned curs[DSTR];              // 8 KB exclusive starts
    __shared__ unsigned sorted[CAP_T];           // 25.6 KB dl-sorted records
    __shared__ unsigned bsum[512];               // 2 KB scan partials

    const int t = threadIdx.x;
    const int tile = blockIdx.x;
    const int sr = tile / ND, dr = tile % ND;
    const int s0 = sr << SS, d0 = dr << DSH;

    for (int i = t; i < SRCR; i += 512) {
        int n = s0 + i;
        float2 p = (n < N) ? x[n] : make_float2(0.f, 0.f);
        xs_x[i] = p.x; xs_y[i] = p.y;
    }
    for (int i = t; i < DSTR; i += 512) cnt[i] = 0u;
    __syncthreads();

    // Phase B: stream records; dl-histogram via ds_add_rtn; stash in regs.
    const unsigned total = min(gcur[tile], (unsigned)CAP_T) & ~3u;
    const unsigned n4 = total >> 2;
    const uint4* r4 = (const uint4*)(records + (size_t)tile * CAP_T);
    unsigned rc[16];
    unsigned sl[16];
#pragma unroll
    for (int i = 0; i < 4; ++i) {
        unsigned j = (unsigned)t + (unsigned)i * 512u;
        uint4 rr = (j < n4) ? r4[j] : make_uint4(SENT, SENT, SENT, SENT);
        unsigned rs[4] = {rr.x, rr.y, rr.z, rr.w};
#pragma unroll
        for (int k = 0; k < 4; ++k) {
            int idx = i * 4 + k;
            rc[idx] = rs[k];
            if (rs[k] != SENT)
                sl[idx] = atomicAdd(&cnt[rs[k] & (DSTR - 1)], 1u);
        }
    }
    __syncthreads();

    // Phase C: hierarchical exclusive scan of cnt into curs.
    unsigned c0 = cnt[4 * t], c1 = cnt[4 * t + 1],
             c2 = cnt[4 * t + 2], c3 = cnt[4 * t + 3];
    unsigned ts = c0 + c1 + c2 + c3;
    bsum[t] = ts;
    __syncthreads();
    for (int off = 1; off < 512; off <<= 1) {
        unsigned a = bsum[t] + ((t >= off) ? bsum[t - off] : 0u);
        __syncthreads();
        bsum[t] = a;
        __syncthreads();
    }
    {
        unsigned e = bsum[t] - ts;                 // exclusive base
        curs[4 * t]     = e;
        curs[4 * t + 1] = e + c0;
        curs[4 * t + 2] = e + c0 + c1;
        curs[4 * t + 3] = e + c0 + c1 + c2;
    }
    __syncthreads();

    // Phase D: atomic-free placement into dl-sorted order.
#pragma unroll
    for (int j = 0; j < 16; ++j)
        if (rc[j] != SENT)
            sorted[curs[rc[j] & (DSTR - 1)] + sl[j]] = rc[j];
    __syncthreads();

    // Phase E: each thread owns 4 dl nodes; serial register reduction.
    float* pt = (float*)(records + (size_t)tile * CAP_T);  // partials alias
#pragma unroll
    for (int q = 0; q < 4; ++q) {
        int dl = t + q * 512;
        int n  = d0 + dl;
        float2 xd = (n < N) ? x[n] : make_float2(0.f, 0.f);
        unsigned beg = curs[dl];
        unsigned end = beg + cnt[dl];
        float ax = 0.f, ay = 0.f;
        for (unsigned i = beg; i < end; ++i) {
            unsigned rec = sorted[i];
            int slc = (int)(rec >> DSH);
            float2 m = lj_msg(xs_x[slc], xs_y[slc], xd.x, xd.y);
            ax += m.x; ay += m.y;
        }
        pt[dl]        = ax;
        pt[DSTR + dl] = ay;
    }
}

// ---- Pass 3: fold NS partials per node + fuse -gamma*v --------------------
__global__ __launch_bounds__(256) void reduce_kernel(
    const float* __restrict__ partials, const float2* __restrict__ v,
    float2* __restrict__ out, int N)
{
    int n = blockIdx.x * 256 + threadIdx.x;
    if (n >= N) return;
    int dr = n >> DSH, dl = n & (DSTR - 1);
    float sx = 0.f, sy = 0.f;
#pragma unroll
    for (int sr = 0; sr < NS; ++sr) {
        const float* pt = partials + (size_t)(sr * ND + dr) * CAP_T;
        sx += pt[dl];
        sy += pt[DSTR + dl];
    }
    float2 vv = v[n];
    out[n] = make_float2(sx - GAMMA * vv.x, sy - GAMMA * vv.y);
}

// ---- Fallback (round-1 path) ----------------------------------------------
__global__ __launch_bounds__(256) void init_kernel(const float4* __restrict__ v,
                                                   float4* __restrict__ out,
                                                   int n4) {
    int i = blockIdx.x * blockDim.x + threadIdx.x;
    if (i < n4) {
        float4 t = v[i];
        out[i] = make_float4(-GAMMA * t.x, -GAMMA * t.y, -GAMMA * t.z, -GAMMA * t.w);
    }
}

__global__ __launch_bounds__(256) void edge_atomic_kernel(
    const float2* __restrict__ x, const int* __restrict__ src,
    const int* __restrict__ dst, float* __restrict__ out, int nE)
{
    int e = blockIdx.x * blockDim.x + threadIdx.x;
    if (e >= nE) return;
    int s = src[e], d = dst[e];
    float2 m = lj_msg(x[s].x, x[s].y, x[d].x, x[d].y);
    unsafeAtomicAdd(&out[2 * d],     m.x);
    unsafeAtomicAdd(&out[2 * d + 1], m.y);
}

extern "C" void kernel_launch(void* const* d_in, const int* in_sizes, int n_in,
                              void* d_out, int out_size, void* d_ws, size_t ws_size,
                              hipStream_t stream) {
    const float* x   = (const float*)d_in[0];
    const float* v   = (const float*)d_in[1];
    const int*   src = (const int*)d_in[2];
    const int*   dst = (const int*)d_in[3];
    float* out = (float*)d_out;

    const int nE = in_sizes[2];                 // 6,400,000
    const int N  = in_sizes[0] / 2;             // 100,000

    const size_t gcur_bytes    = 8192;          // NTA u32, 16B-aligned
    const size_t records_bytes = (size_t)NT * CAP_T * sizeof(unsigned); // 31.4MB
    const size_t needed = gcur_bytes + records_bytes;

    const bool shapes_ok = (N <= NS * SRCR) && (N <= ND * DSTR) && (nE % 4) == 0;

    if (shapes_ok && ws_size >= needed) {
        unsigned* gcur    = (unsigned*)d_ws;
        unsigned* records = (unsigned*)((char*)d_ws + gcur_bytes);
        const int nblk = (nE + CHUNK - 1) / CHUNK;   // 391

        zero_kernel<<<(NTA + 255) / 256, 256, 0, stream>>>(gcur, NTA);
        sort_kernel<<<nblk, STHREADS, 0, stream>>>(
            (const int4*)src, (const int4*)dst, records, gcur, nE);
        tile_kernel<<<NT, 512, 0, stream>>>(
            (const float2*)x, records, gcur, N);
        reduce_kernel<<<(N + 255) / 256, 256, 0, stream>>>(
            (const float*)records, (const float2*)v, (float2*)out, N);
    } else {
        int n4 = out_size / 4;
        init_kernel<<<(n4 + 255) / 256, 256, 0, stream>>>(
            (const float4*)v, (float4*)out, n4);
        edge_atomic_kernel<<<(nE + 255) / 256, 256, 0, stream>>>(
            (const float2*)x, src, dst, out, nE);
    }
}

// Round 7
// 178.227 us; speedup vs baseline: 1.2758x; 1.0029x over previous
//
#include <hip/hip_runtime.h>

// interactionModule: LJ force message passing on a random graph.
//   dr = x[dst]-x[src]; r=|dr|; rc=max(r,0.1)
//   f = 4*(1/rc)^6*(12*(1/rc)^6-6)/rc ; msg = f*dr/max(r,1e-12)
//   out[dst] += msg (segment sum);  out -= 0.1*v
//
// Empirical law (R1-R6, 6 configs): every scatter primitive (LDS atomic,
// divergent vmem, global atomic) costs ~4.3 cyc/lane/CU => ~45us per
// 6.4M-edge scatter pass. Pipeline = 2 scatter passes (tile-key sort,
// per-tile dl-histogram) + streaming => ~90us structural floor.
// R6: sort 50.7us (1 rtn-atomic/edge), tile <50 (1 rtn-atomic/edge). Total 178.7.
// R7 trims: shuffle-based scans (22->2 / 18->2 barriers), interleaved float2
// partials -> reduce does coalesced float4 loads, 2 nodes/thread.

constexpr float GAMMA = 0.1f;
constexpr float MIN_R = 0.1f;
constexpr float EPSN  = 1e-12f;

constexpr int SS   = 12;              // src-range shift (4096 nodes)
constexpr int DSH  = 11;              // dst-range shift (2048 nodes)
constexpr int SRCR = 1 << SS;         // 4096
constexpr int DSTR = 1 << DSH;        // 2048
constexpr int NS   = 25;              // ceil(100000/4096)
constexpr int ND   = 49;              // ceil(100000/2048)
constexpr int NT   = NS * ND;         // 1225 tiles
constexpr int NTA  = 1232;            // padded (>= 2*613, zero-filled tail)
constexpr int CHUNK    = 16384;       // edges per sort block
constexpr int STHREADS = 1024;
constexpr int K        = CHUNK / STHREADS;   // 16 edges/thread
constexpr int CAP_T    = 6400;        // records cap per tile (mean ~5811 incl
                                      // 16B pad, ~7.7 sigma margin)
constexpr unsigned SENT = 0xFFFFFFFFu;

__device__ __forceinline__ float2 lj_msg(float xsx, float xsy, float xdx, float xdy) {
    float dx = xdx - xsx;
    float dy = xdy - xsy;
    float ab = sqrtf(dx * dx + dy * dy);      // |dr| unclamped
    float r  = ab > MIN_R ? ab : MIN_R;       // clamp for force only
    float inv = 1.0f / r;
    float s2 = inv * inv;
    float s6 = s2 * s2 * s2;                  // (1/r)^6
    float f  = 4.0f * s6 * (12.0f * s6 - 6.0f) * inv;
    float c  = f / fmaxf(ab, EPSN);           // F.normalize eps
    return make_float2(c * dx, c * dy);
}

__global__ __launch_bounds__(256) void zero_kernel(unsigned* __restrict__ p, int n) {
    int i = blockIdx.x * blockDim.x + threadIdx.x;
    if (i < n) p[i] = 0u;
}

// ---- Pass 1: counting sort by 2D tile key; ONE atomic per edge ------------
__global__ __launch_bounds__(STHREADS) void sort_kernel(
    const int4* __restrict__ src4, const int4* __restrict__ dst4,
    unsigned* __restrict__ records, unsigned* __restrict__ gcur, int nE)
{
    __shared__ unsigned sorted[CHUNK];    // 64 KB
    __shared__ unsigned cnt[NTA];         // 4.9 KB (zero-padded tail)
    __shared__ unsigned curs[NTA];        // 4.9 KB exclusive starts
    __shared__ unsigned gbase[NTA];       // 4.9 KB
    __shared__ unsigned wsum[16];         // cross-wave scan partials

    const int t = threadIdx.x;
    const int base4 = blockIdx.x * (CHUNK / 4);

    for (int i = t; i < NTA; i += STHREADS) cnt[i] = 0u;
    __syncthreads();

    // Phase A: single read; count via ds_add_rtn, stash (rec, slot) in regs.
    unsigned rc[K];                       // record, SENT = invalid
    unsigned bb[K];                       // tile key
    unsigned sl[K];                       // slot within (block, tile)
#pragma unroll
    for (int i = 0; i < K / 4; ++i) {
        int idx4 = base4 + i * STHREADS + t;
        bool vld = (idx4 * 4) < nE;
        int4 s4 = vld ? src4[idx4] : make_int4(0, 0, 0, 0);
        int4 d4 = vld ? dst4[idx4] : make_int4(0, 0, 0, 0);
        int ss_[4] = {s4.x, s4.y, s4.z, s4.w};
        int dd_[4] = {d4.x, d4.y, d4.z, d4.w};
#pragma unroll
        for (int k = 0; k < 4; ++k) {
            int j = i * 4 + k;
            if (vld) {
                unsigned b = (unsigned)((ss_[k] >> SS) * ND + (dd_[k] >> DSH));
                rc[j] = ((unsigned)(ss_[k] & (SRCR - 1)) << DSH)
                      | (unsigned)(dd_[k] & (DSTR - 1));
                bb[j] = b;
                sl[j] = atomicAdd(&cnt[b], 1u);   // ds_add_rtn_u32
            } else {
                rc[j] = SENT; bb[j] = SENT;
            }
        }
    }
    __syncthreads();

    // Phase B: exclusive scan of cnt[0..NT) into curs via wave shuffles.
    // Threads 0..612 own element pairs (2t, 2t+1); 613*2=1226 covers NT=1225.
    {
        const unsigned lane = t & 63, wv = t >> 6;
        unsigned cA = 0, cB = 0;
        if (t < 613) { cA = cnt[2 * t]; cB = cnt[2 * t + 1]; }
        unsigned ps = cA + cB;
        unsigned sc = ps;
#pragma unroll
        for (int off = 1; off < 64; off <<= 1) {
            unsigned u = __shfl_up(sc, off, 64);
            if ((int)lane >= off) sc += u;
        }
        if (lane == 63) wsum[wv] = sc;
        __syncthreads();
        unsigned base = 0;
        for (unsigned w = 0; w < wv; ++w) base += wsum[w];
        unsigned excl = base + sc - ps;
        if (t < 613) {
            if (2 * t < NT)     curs[2 * t]     = excl;
            if (2 * t + 1 < NT) curs[2 * t + 1] = excl + cA;
        }
    }

    // Phase C: reserve 16B-aligned global ranges (1 atomic per block,tile).
    for (int b = t; b < NT; b += STHREADS) {
        unsigned c = cnt[b];
        unsigned pc = (c + 3u) & ~3u;              // pad to 4 u32 = 16 B
        gbase[b] = pc ? atomicAdd(&gcur[b], pc) : 0u;
    }
    __syncthreads();

    // Phase D: atomic-free placement (excl start + stashed slot).
#pragma unroll
    for (int j = 0; j < K; ++j)
        if (bb[j] != SENT) sorted[curs[bb[j]] + sl[j]] = rc[j];
    __syncthreads();

    // Phase E: flush, one wave per tile; sentinel-pad to 16B multiple.
    const int wave = t >> 6, lane = t & 63;
    for (int b = wave; b < NT; b += STHREADS / 64) {
        unsigned c = cnt[b];
        if (!c) continue;
        unsigned pc = (c + 3u) & ~3u;
        unsigned p = curs[b];                      // exclusive start
        unsigned g = gbase[b];
        unsigned* rb = records + (size_t)b * CAP_T;
        for (unsigned i = lane; i < pc; i += 64) {
            unsigned go = g + i;
            if (go < (unsigned)CAP_T) rb[go] = (i < c) ? sorted[p + i] : SENT;
        }
    }
}

// ---- Pass 2: per tile: dl-sort (1 atomic/edge) + register reduction -------
__global__ __launch_bounds__(512) void tile_kernel(
    const float2* __restrict__ x, unsigned* __restrict__ records,
    const unsigned* __restrict__ gcur, int N)
{
    __shared__ float    xs_x[SRCR], xs_y[SRCR];  // 32 KB src slice
    __shared__ unsigned cnt[DSTR];               // 8 KB per-dl counts
    __shared__ unsigned curs[DSTR];              // 8 KB exclusive starts
    __shared__ unsigned sorted[CAP_T];           // 25.6 KB dl-sorted records
    __shared__ unsigned wsum[8];                 // cross-wave scan partials

    const int t = threadIdx.x;
    const int tile = blockIdx.x;
    const int sr = tile / ND, dr = tile % ND;
    const int s0 = sr << SS, d0 = dr << DSH;

    for (int i = t; i < SRCR; i += 512) {
        int n = s0 + i;
        float2 p = (n < N) ? x[n] : make_float2(0.f, 0.f);
        xs_x[i] = p.x; xs_y[i] = p.y;
    }
    for (int i = t; i < DSTR; i += 512) cnt[i] = 0u;
    __syncthreads();

    // Phase B: stream records; dl-histogram via ds_add_rtn; stash in regs.
    const unsigned total = min(gcur[tile], (unsigned)CAP_T) & ~3u;
    const unsigned n4 = total >> 2;
    const uint4* r4 = (const uint4*)(records + (size_t)tile * CAP_T);
    unsigned rc[16];
    unsigned sl[16];
#pragma unroll
    for (int i = 0; i < 4; ++i) {
        unsigned j = (unsigned)t + (unsigned)i * 512u;
        uint4 rr = (j < n4) ? r4[j] : make_uint4(SENT, SENT, SENT, SENT);
        unsigned rs[4] = {rr.x, rr.y, rr.z, rr.w};
#pragma unroll
        for (int k = 0; k < 4; ++k) {
            int idx = i * 4 + k;
            rc[idx] = rs[k];
            if (rs[k] != SENT)
                sl[idx] = atomicAdd(&cnt[rs[k] & (DSTR - 1)], 1u);
        }
    }
    __syncthreads();

    // Phase C: exclusive scan of cnt into curs via wave shuffles.
    unsigned c0 = cnt[4 * t], c1 = cnt[4 * t + 1],
             c2 = cnt[4 * t + 2], c3 = cnt[4 * t + 3];
    unsigned ts = c0 + c1 + c2 + c3;
    {
        const unsigned lane = t & 63, wv = t >> 6;
        unsigned sc = ts;
#pragma unroll
        for (int off = 1; off < 64; off <<= 1) {
            unsigned u = __shfl_up(sc, off, 64);
            if ((int)lane >= off) sc += u;
        }
        if (lane == 63) wsum[wv] = sc;
        __syncthreads();
        unsigned base = 0;
        for (unsigned w = 0; w < wv; ++w) base += wsum[w];
        unsigned e = base + sc - ts;               // exclusive base
        curs[4 * t]     = e;
        curs[4 * t + 1] = e + c0;
        curs[4 * t + 2] = e + c0 + c1;
        curs[4 * t + 3] = e + c0 + c1 + c2;
    }
    __syncthreads();

    // Phase D: atomic-free placement into dl-sorted order.
#pragma unroll
    for (int j = 0; j < 16; ++j)
        if (rc[j] != SENT)
            sorted[curs[rc[j] & (DSTR - 1)] + sl[j]] = rc[j];
    __syncthreads();

    // Phase E: each thread owns 4 dl nodes; serial register reduction.
    // Partials interleaved (ax,ay) per dl -> reduce reads coalesced float4.
    float2* pt2 = (float2*)(records + (size_t)tile * CAP_T);  // 16KB <= 25.6KB
#pragma unroll
    for (int q = 0; q < 4; ++q) {
        int dl = t + q * 512;
        int n  = d0 + dl;
        float2 xd = (n < N) ? x[n] : make_float2(0.f, 0.f);
        unsigned beg = curs[dl];
        unsigned end = beg + cnt[dl];
        float ax = 0.f, ay = 0.f;
        for (unsigned i = beg; i < end; ++i) {
            unsigned rec = sorted[i];
            int slc = (int)(rec >> DSH);
            float2 m = lj_msg(xs_x[slc], xs_y[slc], xd.x, xd.y);
            ax += m.x; ay += m.y;
        }
        pt2[dl] = make_float2(ax, ay);
    }
}

// ---- Pass 3: fold NS partials per node pair + fuse -gamma*v ---------------
// One thread = 2 nodes = 1 float4 of output; partials reads are float4,
// consecutive threads -> consecutive addresses (fully coalesced).
__global__ __launch_bounds__(256) void reduce_kernel(
    const float* __restrict__ partials, const float4* __restrict__ v4,
    float4* __restrict__ out4, int n4out)
{
    int m = blockIdx.x * 256 + threadIdx.x;      // node pair index
    if (m >= n4out) return;
    int n0 = 2 * m;
    int dr = n0 >> DSH;
    int dl0 = n0 & (DSTR - 1);                   // even
    float sx0 = 0.f, sy0 = 0.f, sx1 = 0.f, sy1 = 0.f;
#pragma unroll
    for (int sr = 0; sr < NS; ++sr) {
        const float4* pt = (const float4*)(partials + (size_t)(sr * ND + dr) * CAP_T);
        float4 p = pt[dl0 >> 1];                 // (ax0,ay0,ax1,ay1)
        sx0 += p.x; sy0 += p.y; sx1 += p.z; sy1 += p.w;
    }
    float4 vv = v4[m];
    out4[m] = make_float4(sx0 - GAMMA * vv.x, sy0 - GAMMA * vv.y,
                          sx1 - GAMMA * vv.z, sy1 - GAMMA * vv.w);
}

// ---- Fallback (round-1 path) ----------------------------------------------
__global__ __launch_bounds__(256) void init_kernel(const float4* __restrict__ v,
                                                   float4* __restrict__ out,
                                                   int n4) {
    int i = blockIdx.x * blockDim.x + threadIdx.x;
    if (i < n4) {
        float4 t = v[i];
        out[i] = make_float4(-GAMMA * t.x, -GAMMA * t.y, -GAMMA * t.z, -GAMMA * t.w);
    }
}

__global__ __launch_bounds__(256) void edge_atomic_kernel(
    const float2* __restrict__ x, const int* __restrict__ src,
    const int* __restrict__ dst, float* __restrict__ out, int nE)
{
    int e = blockIdx.x * blockDim.x + threadIdx.x;
    if (e >= nE) return;
    int s = src[e], d = dst[e];
    float2 m = lj_msg(x[s].x, x[s].y, x[d].x, x[d].y);
    unsafeAtomicAdd(&out[2 * d],     m.x);
    unsafeAtomicAdd(&out[2 * d + 1], m.y);
}

extern "C" void kernel_launch(void* const* d_in, const int* in_sizes, int n_in,
                              void* d_out, int out_size, void* d_ws, size_t ws_size,
                              hipStream_t stream) {
    const float* x   = (const float*)d_in[0];
    const float* v   = (const float*)d_in[1];
    const int*   src = (const int*)d_in[2];
    const int*   dst = (const int*)d_in[3];
    float* out = (float*)d_out;

    const int nE = in_sizes[2];                 // 6,400,000
    const int N  = in_sizes[0] / 2;             // 100,000

    const size_t gcur_bytes    = 8192;          // NTA u32, 16B-aligned
    const size_t records_bytes = (size_t)NT * CAP_T * sizeof(unsigned); // 31.4MB
    const size_t needed = gcur_bytes + records_bytes;

    const bool shapes_ok = (N <= NS * SRCR) && (N <= ND * DSTR) &&
                           (nE % 4) == 0 && (N % 2) == 0 &&
                           (out_size % 4) == 0;

    if (shapes_ok && ws_size >= needed) {
        unsigned* gcur    = (unsigned*)d_ws;
        unsigned* records = (unsigned*)((char*)d_ws + gcur_bytes);
        const int nblk = (nE + CHUNK - 1) / CHUNK;   // 391

        zero_kernel<<<(NTA + 255) / 256, 256, 0, stream>>>(gcur, NTA);
        sort_kernel<<<nblk, STHREADS, 0, stream>>>(
            (const int4*)src, (const int4*)dst, records, gcur, nE);
        tile_kernel<<<NT, 512, 0, stream>>>(
            (const float2*)x, records, gcur, N);
        const int n4out = out_size / 4;              // 50,000 node pairs
        reduce_kernel<<<(n4out + 255) / 256, 256, 0, stream>>>(
            (const float*)records, (const float4*)v, (float4*)out, n4out);
    } else {
        int n4 = out_size / 4;
        init_kernel<<<(n4 + 255) / 256, 256, 0, stream>>>(
            (const float4*)v, (float4*)out, n4);
        edge_atomic_kernel<<<(nE + 255) / 256, 256, 0, stream>>>(
            (const float2*)x, src, dst, out, nE);
    }
}